// Round 1
// baseline (457.368 us; speedup 1.0000x reference)
//
#include <hip/hip_runtime.h>

// ---------------------------------------------------------------------------
// AuxModelImageRotation: rot90 x4 batch expansion -> 3 convs -> fc1 -> fc2
// Round 1: correctness-first fp32. All convs + fc1 as im2col-style tiled GEMM.
// Output layout: [logits 256*4][labels 256][rotated 256*3*128*128], all f32.
// ---------------------------------------------------------------------------

#define TM 64
#define TK 64

// ---------------- rotation (exact permutation) -----------------------------
__global__ __launch_bounds__(256) void rotate_kernel(const float* __restrict__ obs,
                                                     float* __restrict__ rot)
{
    int idx = blockIdx.x * 256 + threadIdx.x;        // 0 .. 12582911
    int w    = idx & 127;
    int h    = (idx >> 7) & 127;
    int cimg = idx >> 14;                            // (a*64+b)*3 + c, 0..767
    int c    = cimg % 3;
    int img  = cimg / 3;                             // 0..255
    int a    = img >> 6;
    int b    = img & 63;
    int hs, ws;
    switch (a) {
        case 0:  hs = h;        ws = w;        break;
        case 1:  hs = w;        ws = 127 - h;  break;   // rot90 k=1: out[h,w]=in[w,127-h]
        case 2:  hs = 127 - h;  ws = 127 - w;  break;
        default: hs = 127 - w;  ws = h;        break;   // k=3: out[h,w]=in[127-w,h]
    }
    rot[idx] = obs[((b * 3 + c) << 14) + (hs << 7) + ws];
}

__global__ void labels_kernel(float* __restrict__ lab)
{
    int i = threadIdx.x;                             // 256 threads
    lab[i] = (float)(i >> 6);
}

// ---------------- conv as implicit GEMM ------------------------------------
// M = 256*OH*OW (n,oh,ow), N = OC, K = IC*KH*KW. Tile TMxTN, K-step TK.
// 256 threads; thread (tm,tn) computes 4 m-rows x NB n-cols.
template<int IC, int IH, int IW, int OC, int KH, int KW, int S, int OH, int OW, int TN>
__global__ __launch_bounds__(256) void conv_gemm(const float* __restrict__ in,
                                                 const float* __restrict__ wt,
                                                 const float* __restrict__ bias,
                                                 float* __restrict__ out)
{
    constexpr int NB = TN / 16;
    constexpr int K  = IC * KH * KW;
    __shared__ __align__(16) float a_lds[TK][TM + 4];
    __shared__ __align__(16) float b_lds[TK][TN + 4];

    const int t  = threadIdx.x;
    const int m0 = blockIdx.x * TM;
    const int n0 = blockIdx.y * TN;
    const int tm = t & 15;
    const int tn = t >> 4;

    float acc[4][NB];
    #pragma unroll
    for (int i = 0; i < 4; ++i)
        #pragma unroll
        for (int j = 0; j < NB; ++j) acc[i][j] = 0.f;

    for (int k0 = 0; k0 < K; k0 += TK) {
        // A tile: im2col gather, lanes walk ml (consecutive ow) for coalescing
        #pragma unroll
        for (int j = 0; j < TM * TK / 256; ++j) {
            int i  = j * 256 + t;
            int ml = i & (TM - 1);
            int kk = i >> 6;
            int m = m0 + ml, k = k0 + kk;
            int n   = m / (OH * OW);
            int rem = m - n * (OH * OW);
            int oh  = rem / OW;
            int ow  = rem - oh * OW;
            int ic  = k / (KH * KW);
            int r2  = k - ic * (KH * KW);
            int kh  = r2 / KW;
            int kw  = r2 - kh * KW;
            a_lds[kk][ml] = in[((n * IC + ic) * IH + oh * S + kh) * IW + ow * S + kw];
        }
        // B tile: weights are [OC][K] row-major -> lanes walk kk (contiguous)
        #pragma unroll
        for (int j = 0; j < TN * TK / 256; ++j) {
            int i  = j * 256 + t;
            int kk = i & (TK - 1);
            int jl = i >> 6;
            b_lds[kk][jl] = wt[(n0 + jl) * K + k0 + kk];
        }
        __syncthreads();

        #pragma unroll 16
        for (int kk = 0; kk < TK; ++kk) {
            float4 av = *(const float4*)&a_lds[kk][tm * 4];
            #pragma unroll
            for (int jn = 0; jn < NB; ++jn) {
                float bv = b_lds[kk][tn * NB + jn];
                acc[0][jn] += av.x * bv;
                acc[1][jn] += av.y * bv;
                acc[2][jn] += av.z * bv;
                acc[3][jn] += av.w * bv;
            }
        }
        __syncthreads();
    }

    // epilogue: bias + relu, scatter back to NCHW
    #pragma unroll
    for (int i4 = 0; i4 < 4; ++i4) {
        int m   = m0 + tm * 4 + i4;
        int n   = m / (OH * OW);
        int rem = m - n * (OH * OW);
        int oh  = rem / OW;
        int ow  = rem - oh * OW;
        #pragma unroll
        for (int jn = 0; jn < NB; ++jn) {
            int oc  = n0 + tn * NB + jn;
            float v = acc[i4][jn] + bias[oc];
            v = v > 0.f ? v : 0.f;
            out[((n * OC + oc) * OH + oh) * OW + ow] = v;
        }
    }
}

// ---------------- fc1: [256,9216] @ [9216,512]^T, split-K=8 ----------------
__global__ __launch_bounds__(256) void fc_gemm(const float* __restrict__ A,
                                               const float* __restrict__ W,
                                               float* __restrict__ outp) // [8][256][512]
{
    __shared__ __align__(16) float a_lds[64][68];
    __shared__ __align__(16) float b_lds[64][36];
    const int t     = threadIdx.x;
    const int m0    = blockIdx.x * 64;   // 4 blocks
    const int n0    = blockIdx.y * 32;   // 16 blocks
    const int z     = blockIdx.z;        // 8 splits
    const int kbase = z * 1152;
    const int tm = t & 15, tn = t >> 4;

    float acc[4][2] = {{0.f, 0.f}, {0.f, 0.f}, {0.f, 0.f}, {0.f, 0.f}};

    for (int k0 = 0; k0 < 1152; k0 += 64) {
        #pragma unroll
        for (int j = 0; j < 16; ++j) {         // A: kk-fast (contiguous rows)
            int i  = j * 256 + t;
            int kk = i & 63, ml = i >> 6;
            a_lds[kk][ml] = A[(m0 + ml) * 9216 + kbase + k0 + kk];
        }
        #pragma unroll
        for (int j = 0; j < 8; ++j) {          // B: kk-fast
            int i  = j * 256 + t;
            int kk = i & 63, jl = i >> 6;
            b_lds[kk][jl] = W[(n0 + jl) * 9216 + kbase + k0 + kk];
        }
        __syncthreads();
        #pragma unroll 16
        for (int kk = 0; kk < 64; ++kk) {
            float4 av = *(const float4*)&a_lds[kk][tm * 4];
            #pragma unroll
            for (int jn = 0; jn < 2; ++jn) {
                float bv = b_lds[kk][tn * 2 + jn];
                acc[0][jn] += av.x * bv;
                acc[1][jn] += av.y * bv;
                acc[2][jn] += av.z * bv;
                acc[3][jn] += av.w * bv;
            }
        }
        __syncthreads();
    }
    #pragma unroll
    for (int i4 = 0; i4 < 4; ++i4) {
        int m = m0 + tm * 4 + i4;
        #pragma unroll
        for (int jn = 0; jn < 2; ++jn) {
            int n = n0 + tn * 2 + jn;
            outp[(z * 256 + m) * 512 + n] = acc[i4][jn];
        }
    }
}

// ---------------- fc2: combine split-K, bias, relu, final 512-dot ----------
__global__ __launch_bounds__(256) void fc2_kernel(const float* __restrict__ hp, // [8][256][512]
                                                  const float* __restrict__ b1,
                                                  const float* __restrict__ W2, // [4][512]
                                                  const float* __restrict__ b2,
                                                  float* __restrict__ logits)   // [256][4]
{
    __shared__ float s[512];
    const int i = blockIdx.x;     // batch row
    const int t = threadIdx.x;
    for (int k = t; k < 512; k += 256) {
        float v = b1[k];
        #pragma unroll
        for (int z = 0; z < 8; ++z) v += hp[(z * 256 + i) * 512 + k];
        s[k] = v > 0.f ? v : 0.f;
    }
    __syncthreads();
    const int j = t >> 6;         // wave -> output neuron 0..3
    const int l = t & 63;
    float p = 0.f;
    #pragma unroll
    for (int q = 0; q < 8; ++q) p += s[l + q * 64] * W2[j * 512 + l + q * 64];
    #pragma unroll
    for (int off = 32; off > 0; off >>= 1) p += __shfl_xor(p, off);
    if (l == 0) logits[i * 4 + j] = p + b2[j];
}

// ---------------------------------------------------------------------------
extern "C" void kernel_launch(void* const* d_in, const int* in_sizes, int n_in,
                              void* d_out, int out_size, void* d_ws, size_t ws_size,
                              hipStream_t stream)
{
    const float* obs   = (const float*)d_in[0];
    const float* w1    = (const float*)d_in[1];
    const float* b1    = (const float*)d_in[2];
    const float* w2    = (const float*)d_in[3];
    const float* b2    = (const float*)d_in[4];
    const float* w3    = (const float*)d_in[5];
    const float* b3    = (const float*)d_in[6];
    const float* fc1_w = (const float*)d_in[7];
    const float* fc1_b = (const float*)d_in[8];
    const float* fc2_w = (const float*)d_in[9];
    const float* fc2_b = (const float*)d_in[10];

    float* out    = (float*)d_out;
    float* logits = out;                 // 1024
    float* labels = out + 1024;          // 256
    float* rot    = out + 1280;          // 256*3*128*128

    char* ws = (char*)d_ws;
    // act1 [256,32,31,31] @0 (31,490,048 B); act2 @31,490,048 (12,845,056 B)
    // act3 [256,9216]     @0 (9,437,184 B, act1 dead); h_part @9,437,184 (1 MB)
    float* act1  = (float*)(ws);
    float* act2  = (float*)(ws + 31490048);
    float* act3  = (float*)(ws);
    float* hpart = (float*)(ws + 9437184);

    // 1. rotation + labels
    rotate_kernel<<<49152, 256, 0, stream>>>(obs, rot);
    labels_kernel<<<1, 256, 0, stream>>>(labels);

    // 2. conv1: 3x128x128 -> 32x31x31 (k8 s4), M=246016 K=192 N=32
    conv_gemm<3, 128, 128, 32, 8, 8, 4, 31, 31, 32>
        <<<dim3(246016 / TM, 1), 256, 0, stream>>>(rot, w1, b1, act1);

    // 3. conv2: 32x31x31 -> 64x14x14 (k4 s2), M=50176 K=512 N=64
    conv_gemm<32, 31, 31, 64, 4, 4, 2, 14, 14, 64>
        <<<dim3(50176 / TM, 1), 256, 0, stream>>>(act1, w2, b2, act2);

    // 4. conv3: 64x14x14 -> 64x12x12 (k3 s1), M=36864 K=576 N=64
    conv_gemm<64, 14, 14, 64, 3, 3, 1, 12, 12, 64>
        <<<dim3(36864 / TM, 1), 256, 0, stream>>>(act2, w3, b3, act3);

    // 5. fc1 (split-K=8, partials) + 6. fc2 (combine + bias + relu + dot)
    fc_gemm<<<dim3(4, 16, 8), 256, 0, stream>>>(act3, fc1_w, hpart);
    fc2_kernel<<<256, 256, 0, stream>>>(hpart, fc1_b, fc2_w, fc2_b, logits);
}

// Round 2
// 114.042 us; speedup vs baseline: 4.0105x; 4.0105x over previous
//
#include <hip/hip_runtime.h>

// ---------------------------------------------------------------------------
// AuxModelImageRotation round 2: bf16 MFMA everywhere.
// rot (f32, exact, tiled-transpose) -> conv1/2/3 + fc1 as bf16 MFMA im2col
// GEMMs (NHWC activations, XOR-swizzled LDS), fc2 fp32 combine.
// Output: [logits 1024][labels 256][rotated 256*3*128*128] f32.
// ---------------------------------------------------------------------------

typedef short bf16x8 __attribute__((ext_vector_type(8)));
typedef float f32x4  __attribute__((ext_vector_type(4)));

__device__ __forceinline__ ushort f2bf(float f) {
    uint u = __float_as_uint(f);
    u += 0x7fffu + ((u >> 16) & 1u);
    return (ushort)(u >> 16);
}

// ---------------- rotation: LDS-tiled, all 4 angles coalesced --------------
__global__ __launch_bounds__(256) void rotate_tiled(const float* __restrict__ obs,
                                                    float* __restrict__ rot)
{
    __shared__ float s[32][36];
    const int t    = threadIdx.x;
    const int bx   = blockIdx.x;          // 12288 = 768 (img,c) * 16 tiles
    const int tile = bx & 15;
    const int cimg = bx >> 4;             // 0..767
    const int c    = cimg % 3;
    const int img  = cimg / 3;            // a*64+b
    const int a    = img >> 6;
    const int h0   = (tile >> 2) * 32, w0 = (tile & 3) * 32;

    int hs0, ws0;
    switch (a) {
        case 0:  hs0 = h0;      ws0 = w0;      break;
        case 1:  hs0 = w0;      ws0 = 96 - h0; break;
        case 2:  hs0 = 96 - h0; ws0 = 96 - w0; break;
        default: hs0 = 96 - w0; ws0 = h0;      break;
    }
    const int b = img & 63;
    const float* src = obs + (((b * 3 + c) << 14));
    const int rs = t >> 3, w4 = (t & 7) * 4;
    *(float4*)&s[rs][w4] = *(const float4*)&src[((hs0 + rs) << 7) + ws0 + w4];
    __syncthreads();

    const int h = h0 + rs;
    float4 v;
    #pragma unroll
    for (int i = 0; i < 4; ++i) {
        int w = w0 + w4 + i;
        int hs, ws;
        switch (a) {
            case 0:  hs = h;        ws = w;        break;
            case 1:  hs = w;        ws = 127 - h;  break;
            case 2:  hs = 127 - h;  ws = 127 - w;  break;
            default: hs = 127 - w;  ws = h;        break;
        }
        ((float*)&v)[i] = s[hs - hs0][ws - ws0];
    }
    *(float4*)&rot[((img * 3 + c) << 14) + (h << 7) + w0 + w4] = v;
}

__global__ void labels_kernel(float* __restrict__ lab)
{
    int i = threadIdx.x;
    lab[i] = (float)(i >> 6);
}

// ---------------- weight prep: reorder to (kh,kw,ic) bf16 ------------------
__global__ __launch_bounds__(256) void prep_w2(const float* __restrict__ w, ushort* __restrict__ o)
{
    int i = blockIdx.x * 256 + threadIdx.x;          // 32768
    int ic = i & 31, kw = (i >> 5) & 3, kh = (i >> 7) & 3, oc = i >> 9;
    o[i] = f2bf(w[((oc * 32 + ic) * 4 + kh) * 4 + kw]);
}

__global__ __launch_bounds__(256) void prep_w3(const float* __restrict__ w, ushort* __restrict__ o)
{
    int i = blockIdx.x * 256 + threadIdx.x;          // 36864
    int ic = i & 63, r = i >> 6;
    int kw = r % 3, r2 = r / 3;
    int kh = r2 % 3, oc = r2 / 3;
    o[i] = f2bf(w[((oc * 64 + ic) * 3 + kh) * 3 + kw]);
}

// fc1_w [512][64*12*12] (c,h,w order) -> bf16 [512][12*12*64] (h,w,c order)
__global__ __launch_bounds__(256) void prep_fc1w(const float* __restrict__ w, ushort* __restrict__ o)
{
    __shared__ float s[9216];
    const int n = blockIdx.x, t = threadIdx.x;
    #pragma unroll
    for (int j = 0; j < 9; ++j) {
        int i = (j * 256 + t) * 4;
        *(float4*)&s[i] = *(const float4*)&w[n * 9216 + i];
    }
    __syncthreads();
    uint* op = (uint*)(o + n * 9216);
    #pragma unroll
    for (int j = 0; j < 18; ++j) {
        int q  = j * 256 + t;                 // out elems 2q,2q+1
        int jj = q * 2;
        int ic = jj & 63, p = jj >> 6;        // p = oh*12+ow
        uint lo = f2bf(s[ic * 144 + p]);
        uint hi = f2bf(s[(ic + 1) * 144 + p]);
        op[q] = lo | (hi << 16);
    }
}

// ---------------- conv1: rot f32 NCHW -> act1 NHWC bf16, MFMA --------------
// M=246016 (n,oh31,ow31), N=32, K=192 (ic,kh,kw). BM=128, single K pass.
__global__ __launch_bounds__(256) void conv1_mfma(const float* __restrict__ rot,
                                                  const float* __restrict__ w1,
                                                  const float* __restrict__ bias,
                                                  ushort* __restrict__ out)
{
    __shared__ ushort aT[128 * 192];
    __shared__ ushort bT[32 * 192];
    const int t  = threadIdx.x;
    const int m0 = blockIdx.x * 128;

    // A: im2col gather, 8-f32 runs along kw
    #pragma unroll
    for (int j = 0; j < 12; ++j) {
        int tau = j * 256 + t;
        int row = tau & 127;
        int q   = tau >> 7;                  // 0..23
        int ic  = q >> 3, kh = q & 7;
        int m   = m0 + row;
        int n   = m / 961; int rem = m - n * 961;
        int oh  = rem / 31; int ow = rem - oh * 31;
        const float* src = rot + ((n * 3 + ic) << 14) + ((oh * 4 + kh) << 7) + ow * 4;
        float4 v0 = *(const float4*)(src);
        float4 v1 = *(const float4*)(src + 4);
        bf16x8 p;
        p[0] = (short)f2bf(v0.x); p[1] = (short)f2bf(v0.y);
        p[2] = (short)f2bf(v0.z); p[3] = (short)f2bf(v0.w);
        p[4] = (short)f2bf(v1.x); p[5] = (short)f2bf(v1.y);
        p[6] = (short)f2bf(v1.z); p[7] = (short)f2bf(v1.w);
        int k0 = ic * 64 + kh * 8;
        *(bf16x8*)&aT[(row * 192 + k0) ^ ((row & 7) << 3)] = p;
    }
    // B: w1 f32 [32][192], natural (ic,kh,kw) order
    #pragma unroll
    for (int j = 0; j < 3; ++j) {
        int tau = j * 256 + t;
        int row = tau & 31, c = tau >> 5;    // c 0..23
        const float* src = w1 + row * 192 + c * 8;
        float4 v0 = *(const float4*)(src);
        float4 v1 = *(const float4*)(src + 4);
        bf16x8 p;
        p[0] = (short)f2bf(v0.x); p[1] = (short)f2bf(v0.y);
        p[2] = (short)f2bf(v0.z); p[3] = (short)f2bf(v0.w);
        p[4] = (short)f2bf(v1.x); p[5] = (short)f2bf(v1.y);
        p[6] = (short)f2bf(v1.z); p[7] = (short)f2bf(v1.w);
        *(bf16x8*)&bT[(row * 192 + c * 8) ^ ((row & 7) << 3)] = p;
    }
    __syncthreads();

    const int wid = t >> 6, l = t & 63;
    const int lrow = l & 15, lk = (l >> 4) << 3;
    f32x4 acc[2][2] = {};
    #pragma unroll
    for (int s = 0; s < 6; ++s) {
        bf16x8 af[2], bv[2];
        #pragma unroll
        for (int m = 0; m < 2; ++m) {
            int r = wid * 32 + m * 16 + lrow;
            af[m] = *(const bf16x8*)&aT[(r * 192 + s * 32 + lk) ^ ((r & 7) << 3)];
        }
        #pragma unroll
        for (int n = 0; n < 2; ++n) {
            int r = n * 16 + lrow;
            bv[n] = *(const bf16x8*)&bT[(r * 192 + s * 32 + lk) ^ ((r & 7) << 3)];
        }
        #pragma unroll
        for (int m = 0; m < 2; ++m)
            #pragma unroll
            for (int n = 0; n < 2; ++n)
                acc[m][n] = __builtin_amdgcn_mfma_f32_16x16x32_bf16(af[m], bv[n], acc[m][n], 0, 0, 0);
    }
    #pragma unroll
    for (int m = 0; m < 2; ++m)
        #pragma unroll
        for (int n = 0; n < 2; ++n)
            #pragma unroll
            for (int j = 0; j < 4; ++j) {
                int row = m0 + wid * 32 + m * 16 + ((l >> 4) << 2) + j;
                int col = n * 16 + lrow;
                float v = acc[m][n][j] + bias[col];
                v = v > 0.f ? v : 0.f;
                out[row * 32 + col] = f2bf(v);
            }
}

// ---------------- conv2/conv3: NHWC bf16 in/out, MFMA ----------------------
// K-loop over kh; BK = KW*IC contiguous per (row,kh). BM=128, OC=64.
template<int IC, int IH, int IW, int KH, int KW, int S, int OH, int OW>
__global__ __launch_bounds__(256) void conv_mfma(const ushort* __restrict__ in,
                                                 const ushort* __restrict__ wr,
                                                 const float* __restrict__ bias,
                                                 ushort* __restrict__ out)
{
    constexpr int BK  = KW * IC;          // 128 (conv2) / 192 (conv3)
    constexpr int NCH = BK / 8;
    __shared__ ushort aT[128 * BK];
    __shared__ ushort bT[64 * BK];
    const int t  = threadIdx.x;
    const int m0 = blockIdx.x * 128;
    const int wid = t >> 6, l = t & 63;
    const int lrow = l & 15, lk = (l >> 4) << 3;

    f32x4 acc[2][4] = {};
    for (int kh = 0; kh < KH; ++kh) {
        #pragma unroll
        for (int j = 0; j < 128 * NCH / 256; ++j) {
            int tau = j * 256 + t;
            int row = tau / NCH, c = tau - row * NCH;
            int m   = m0 + row;
            int n   = m / (OH * OW); int rem = m - n * (OH * OW);
            int oh  = rem / OW; int ow = rem - oh * OW;
            bf16x8 v = *(const bf16x8*)&in[((n * IH + oh * S + kh) * IW + ow * S) * IC + c * 8];
            *(bf16x8*)&aT[(row * BK + c * 8) ^ ((row & 7) << 3)] = v;
        }
        #pragma unroll
        for (int j = 0; j < 64 * NCH / 256; ++j) {
            int tau = j * 256 + t;
            int row = tau / NCH, c = tau - row * NCH;
            bf16x8 v = *(const bf16x8*)&wr[row * (KH * BK) + kh * BK + c * 8];
            *(bf16x8*)&bT[(row * BK + c * 8) ^ ((row & 7) << 3)] = v;
        }
        __syncthreads();
        #pragma unroll
        for (int s = 0; s < BK / 32; ++s) {
            bf16x8 af[2], bv[4];
            #pragma unroll
            for (int m = 0; m < 2; ++m) {
                int r = wid * 32 + m * 16 + lrow;
                af[m] = *(const bf16x8*)&aT[(r * BK + s * 32 + lk) ^ ((r & 7) << 3)];
            }
            #pragma unroll
            for (int n = 0; n < 4; ++n) {
                int r = n * 16 + lrow;
                bv[n] = *(const bf16x8*)&bT[(r * BK + s * 32 + lk) ^ ((r & 7) << 3)];
            }
            #pragma unroll
            for (int m = 0; m < 2; ++m)
                #pragma unroll
                for (int n = 0; n < 4; ++n)
                    acc[m][n] = __builtin_amdgcn_mfma_f32_16x16x32_bf16(af[m], bv[n], acc[m][n], 0, 0, 0);
        }
        __syncthreads();
    }
    #pragma unroll
    for (int m = 0; m < 2; ++m)
        #pragma unroll
        for (int n = 0; n < 4; ++n)
            #pragma unroll
            for (int j = 0; j < 4; ++j) {
                int row = m0 + wid * 32 + m * 16 + ((l >> 4) << 2) + j;
                int col = n * 16 + lrow;
                float v = acc[m][n][j] + bias[col];
                v = v > 0.f ? v : 0.f;
                out[row * 64 + col] = f2bf(v);
            }
}

// ---------------- fc1: [256,9216]x[512,9216]^T bf16 MFMA, split-K=8 --------
__global__ __launch_bounds__(256) void fc1_mfma(const ushort* __restrict__ A,
                                                const ushort* __restrict__ W,
                                                float* __restrict__ hpart)  // [8][256][512]
{
    __shared__ ushort aT[64 * 64];
    __shared__ ushort bT[64 * 64];
    const int t  = threadIdx.x;
    const int m0 = blockIdx.x * 64, n0 = blockIdx.y * 64;
    const int z  = blockIdx.z;
    const int kb = z * 1152;
    const int wid = t >> 6, l = t & 63;
    const int lrow = l & 15, lk = (l >> 4) << 3;
    const int wm = (wid >> 1) * 32, wn = (wid & 1) * 32;

    f32x4 acc[2][2] = {};
    for (int k0 = 0; k0 < 1152; k0 += 64) {
        #pragma unroll
        for (int j = 0; j < 2; ++j) {
            int tau = j * 256 + t;
            int row = tau >> 3, c = tau & 7;
            bf16x8 v = *(const bf16x8*)&A[(m0 + row) * 9216 + kb + k0 + c * 8];
            *(bf16x8*)&aT[(row * 64 + c * 8) ^ ((row & 7) << 3)] = v;
        }
        #pragma unroll
        for (int j = 0; j < 2; ++j) {
            int tau = j * 256 + t;
            int row = tau >> 3, c = tau & 7;
            bf16x8 v = *(const bf16x8*)&W[(n0 + row) * 9216 + kb + k0 + c * 8];
            *(bf16x8*)&bT[(row * 64 + c * 8) ^ ((row & 7) << 3)] = v;
        }
        __syncthreads();
        #pragma unroll
        for (int s = 0; s < 2; ++s) {
            bf16x8 af[2], bv[2];
            #pragma unroll
            for (int m = 0; m < 2; ++m) {
                int r = wm + m * 16 + lrow;
                af[m] = *(const bf16x8*)&aT[(r * 64 + s * 32 + lk) ^ ((r & 7) << 3)];
            }
            #pragma unroll
            for (int n = 0; n < 2; ++n) {
                int r = wn + n * 16 + lrow;
                bv[n] = *(const bf16x8*)&bT[(r * 64 + s * 32 + lk) ^ ((r & 7) << 3)];
            }
            #pragma unroll
            for (int m = 0; m < 2; ++m)
                #pragma unroll
                for (int n = 0; n < 2; ++n)
                    acc[m][n] = __builtin_amdgcn_mfma_f32_16x16x32_bf16(af[m], bv[n], acc[m][n], 0, 0, 0);
        }
        __syncthreads();
    }
    #pragma unroll
    for (int m = 0; m < 2; ++m)
        #pragma unroll
        for (int n = 0; n < 2; ++n)
            #pragma unroll
            for (int j = 0; j < 4; ++j) {
                int row = m0 + wm + m * 16 + ((l >> 4) << 2) + j;
                int col = n0 + wn + n * 16 + lrow;
                hpart[(z * 256 + row) * 512 + col] = acc[m][n][j];
            }
}

// ---------------- fc2: combine split-K, bias, relu, final 512-dot ----------
__global__ __launch_bounds__(256) void fc2_kernel(const float* __restrict__ hp,
                                                  const float* __restrict__ b1,
                                                  const float* __restrict__ W2,
                                                  const float* __restrict__ b2,
                                                  float* __restrict__ logits)
{
    __shared__ float s[512];
    const int i = blockIdx.x;
    const int t = threadIdx.x;
    for (int k = t; k < 512; k += 256) {
        float v = b1[k];
        #pragma unroll
        for (int z = 0; z < 8; ++z) v += hp[(z * 256 + i) * 512 + k];
        s[k] = v > 0.f ? v : 0.f;
    }
    __syncthreads();
    const int j = t >> 6;
    const int l = t & 63;
    float p = 0.f;
    #pragma unroll
    for (int q = 0; q < 8; ++q) p += s[l + q * 64] * W2[j * 512 + l + q * 64];
    #pragma unroll
    for (int off = 32; off > 0; off >>= 1) p += __shfl_xor(p, off);
    if (l == 0) logits[i * 4 + j] = p + b2[j];
}

// ---------------------------------------------------------------------------
extern "C" void kernel_launch(void* const* d_in, const int* in_sizes, int n_in,
                              void* d_out, int out_size, void* d_ws, size_t ws_size,
                              hipStream_t stream)
{
    const float* obs   = (const float*)d_in[0];
    const float* w1    = (const float*)d_in[1];
    const float* b1    = (const float*)d_in[2];
    const float* w2    = (const float*)d_in[3];
    const float* b2    = (const float*)d_in[4];
    const float* w3    = (const float*)d_in[5];
    const float* b3    = (const float*)d_in[6];
    const float* fc1_w = (const float*)d_in[7];
    const float* fc1_b = (const float*)d_in[8];
    const float* fc2_w = (const float*)d_in[9];
    const float* fc2_b = (const float*)d_in[10];

    float* out    = (float*)d_out;
    float* logits = out;
    float* labels = out + 1024;
    float* rot    = out + 1280;

    char* ws = (char*)d_ws;
    ushort* act1  = (ushort*)(ws);                       // 15,745,024 B
    ushort* act2  = (ushort*)(ws + 15745024);            //  6,422,528 B
    ushort* act3  = (ushort*)(ws + 22167552);            //  4,718,592 B
    ushort* w2r   = (ushort*)(ws + 26886144);            //     65,536 B
    ushort* w3r   = (ushort*)(ws + 26951680);            //     73,728 B
    ushort* fc1wr = (ushort*)(ws + 27025408);            //  9,437,184 B
    float*  hpart = (float*) (ws + 36462592);            //  4,194,304 B

    prep_w2<<<128, 256, 0, stream>>>(w2, w2r);
    prep_w3<<<144, 256, 0, stream>>>(w3, w3r);
    prep_fc1w<<<512, 256, 0, stream>>>(fc1_w, fc1wr);

    rotate_tiled<<<12288, 256, 0, stream>>>(obs, rot);
    labels_kernel<<<1, 256, 0, stream>>>(labels);

    conv1_mfma<<<1922, 256, 0, stream>>>(rot, w1, b1, act1);

    conv_mfma<32, 31, 31, 4, 4, 2, 14, 14><<<392, 256, 0, stream>>>(act1, w2r, b2, act2);
    conv_mfma<64, 14, 14, 3, 3, 1, 12, 12><<<288, 256, 0, stream>>>(act2, w3r, b3, act3);

    fc1_mfma<<<dim3(4, 8, 8), 256, 0, stream>>>(act3, fc1wr, hpart);
    fc2_kernel<<<256, 256, 0, stream>>>(hpart, fc1_b, fc2_w, fc2_b, logits);
}

// Round 3
// 104.874 us; speedup vs baseline: 4.3611x; 1.0874x over previous
//
#include <hip/hip_runtime.h>

// ---------------------------------------------------------------------------
// AuxModelImageRotation round 3.
// Key change: conv1 reads obs DIRECTLY (no rot re-read) using rotated weights
//   conv(rot_a(x), w) = perm_a(conv(x, rot_a'(w)))   [stride4/k8 commutes]
// One GEMM M=61504, N=128 (4 angles x 32 oc), K=192; epilogue scatters the
// inverse output permutation. rotate_tiled only produces the d_out copy.
// conv2/conv3/fc1/fc2 unchanged from round 2 (verified). Preps merged.
// ---------------------------------------------------------------------------

typedef short bf16x8 __attribute__((ext_vector_type(8)));
typedef float f32x4  __attribute__((ext_vector_type(4)));

__device__ __forceinline__ ushort f2bf(float f) {
    uint u = __float_as_uint(f);
    u += 0x7fffu + ((u >> 16) & 1u);
    return (ushort)(u >> 16);
}

// ---------------- rotation (exact permutation, d_out only) -----------------
__global__ __launch_bounds__(256) void rotate_tiled(const float* __restrict__ obs,
                                                    float* __restrict__ rot)
{
    __shared__ float s[32][36];
    const int t    = threadIdx.x;
    const int bx   = blockIdx.x;          // 12288 = 768 (img,c) * 16 tiles
    const int tile = bx & 15;
    const int cimg = bx >> 4;
    const int c    = cimg % 3;
    const int img  = cimg / 3;
    const int a    = img >> 6;
    const int h0   = (tile >> 2) * 32, w0 = (tile & 3) * 32;

    int hs0, ws0;
    switch (a) {
        case 0:  hs0 = h0;      ws0 = w0;      break;
        case 1:  hs0 = w0;      ws0 = 96 - h0; break;
        case 2:  hs0 = 96 - h0; ws0 = 96 - w0; break;
        default: hs0 = 96 - w0; ws0 = h0;      break;
    }
    const int b = img & 63;
    const float* src = obs + (((b * 3 + c) << 14));
    const int rs = t >> 3, w4 = (t & 7) * 4;
    *(float4*)&s[rs][w4] = *(const float4*)&src[((hs0 + rs) << 7) + ws0 + w4];
    __syncthreads();

    const int h = h0 + rs;
    float4 v;
    #pragma unroll
    for (int i = 0; i < 4; ++i) {
        int w = w0 + w4 + i;
        int hs, ws;
        switch (a) {
            case 0:  hs = h;        ws = w;        break;
            case 1:  hs = w;        ws = 127 - h;  break;
            case 2:  hs = 127 - h;  ws = 127 - w;  break;
            default: hs = 127 - w;  ws = h;        break;
        }
        ((float*)&v)[i] = s[hs - hs0][ws - ws0];
    }
    *(float4*)&rot[((img * 3 + c) << 14) + (h << 7) + w0 + w4] = v;
}

// ---------------- merged small preps: w2r, w3r, w1r (rotated), labels ------
__global__ __launch_bounds__(256) void prep_misc(const float* __restrict__ w1,
                                                 const float* __restrict__ w2,
                                                 const float* __restrict__ w3,
                                                 ushort* __restrict__ w1r,
                                                 ushort* __restrict__ w2r,
                                                 ushort* __restrict__ w3r,
                                                 float* __restrict__ lab)
{
    const int bx = blockIdx.x, t = threadIdx.x;
    if (bx < 128) {                       // w2 -> (oc, kh, kw, ic) bf16
        int i = bx * 256 + t;             // 32768
        int ic = i & 31, kw = (i >> 5) & 3, kh = (i >> 7) & 3, oc = i >> 9;
        w2r[i] = f2bf(w2[((oc * 32 + ic) * 4 + kh) * 4 + kw]);
    } else if (bx < 272) {                // w3 -> (oc, kh, kw, ic) bf16
        int i = (bx - 128) * 256 + t;     // 36864
        int ic = i & 63, r = i >> 6;
        int kw = r % 3, r2 = r / 3;
        int kh = r2 % 3, oc = r2 / 3;
        w3r[i] = f2bf(w3[((oc * 64 + ic) * 3 + kh) * 3 + kw]);
    } else if (bx < 368) {                // w1 -> rotated variants [a*32+oc][ic*64+a8*8+b8]
        int i = (bx - 272) * 256 + t;     // 24576
        int n = i / 192, r = i - n * 192;
        int ic = r >> 6, a8 = (r >> 3) & 7, b8 = r & 7;
        int a = n >> 5, oc = n & 31;
        int kh, kw;
        switch (a) {
            case 0:  kh = a8;     kw = b8;     break;
            case 1:  kh = 7 - b8; kw = a8;     break;
            case 2:  kh = 7 - a8; kw = 7 - b8; break;
            default: kh = b8;     kw = 7 - a8; break;
        }
        w1r[i] = f2bf(w1[((oc * 3 + ic) * 8 + kh) * 8 + kw]);
    } else {                              // labels
        lab[t] = (float)(t >> 6);
    }
}

// fc1_w [512][64*12*12] (c,h,w order) -> bf16 [512][12*12*64] (h,w,c order)
__global__ __launch_bounds__(256) void prep_fc1w(const float* __restrict__ w, ushort* __restrict__ o)
{
    __shared__ float s[9216];
    const int n = blockIdx.x, t = threadIdx.x;
    #pragma unroll
    for (int j = 0; j < 9; ++j) {
        int i = (j * 256 + t) * 4;
        *(float4*)&s[i] = *(const float4*)&w[n * 9216 + i];
    }
    __syncthreads();
    uint* op = (uint*)(o + n * 9216);
    #pragma unroll
    for (int j = 0; j < 18; ++j) {
        int q  = j * 256 + t;
        int jj = q * 2;
        int ic = jj & 63, p = jj >> 6;
        uint lo = f2bf(s[ic * 144 + p]);
        uint hi = f2bf(s[(ic + 1) * 144 + p]);
        op[q] = lo | (hi << 16);
    }
}

// ---------------- conv1: obs f32 -> act1 NHWC bf16 via rotated weights -----
// M=61504 (b,p,q over 64 imgs), N=128 (a*32+oc), K=192 (ic,dh,dw). BM=BN=128.
__global__ __launch_bounds__(256) void conv1_mfma(const float* __restrict__ obs,
                                                  const ushort* __restrict__ w1r,
                                                  const float* __restrict__ bias,
                                                  ushort* __restrict__ act1)
{
    __shared__ ushort aT[128 * 64];
    __shared__ ushort bT[128 * 64];
    const int t   = threadIdx.x;
    const int m0  = blockIdx.x * 128;
    const int wid = t >> 6, l = t & 63;
    const int lrow = l & 15, lk = (l >> 4) << 3;
    const int wm = (wid >> 1) * 64, wn = (wid & 1) * 64;

    f32x4 acc[4][4] = {};
    for (int ic = 0; ic < 3; ++ic) {
        #pragma unroll
        for (int j = 0; j < 4; ++j) {                    // A: x-window gather
            int cid = j * 256 + t;                       // 0..1023
            int row = cid >> 3, c = cid & 7;             // c = dh
            int m = m0 + row; m = m < 61504 ? m : 61503;
            int b = m / 961; int rem = m - b * 961;
            int p = rem / 31; int q = rem - p * 31;
            const float* src = obs + ((b * 3 + ic) << 14) + ((p * 4 + c) << 7) + q * 4;
            float4 v0 = *(const float4*)src;
            float4 v1 = *(const float4*)(src + 4);
            bf16x8 pk;
            pk[0] = (short)f2bf(v0.x); pk[1] = (short)f2bf(v0.y);
            pk[2] = (short)f2bf(v0.z); pk[3] = (short)f2bf(v0.w);
            pk[4] = (short)f2bf(v1.x); pk[5] = (short)f2bf(v1.y);
            pk[6] = (short)f2bf(v1.z); pk[7] = (short)f2bf(v1.w);
            *(bf16x8*)&aT[(row * 64 + c * 8) ^ ((row & 7) << 3)] = pk;
        }
        #pragma unroll
        for (int j = 0; j < 4; ++j) {                    // B: rotated weights
            int cid = j * 256 + t;
            int row = cid >> 3, c = cid & 7;
            bf16x8 v = *(const bf16x8*)&w1r[row * 192 + ic * 64 + c * 8];
            *(bf16x8*)&bT[(row * 64 + c * 8) ^ ((row & 7) << 3)] = v;
        }
        __syncthreads();
        #pragma unroll
        for (int s = 0; s < 2; ++s) {
            bf16x8 af[4], bv[4];
            #pragma unroll
            for (int m = 0; m < 4; ++m) {
                int r = wm + m * 16 + lrow;
                af[m] = *(const bf16x8*)&aT[(r * 64 + s * 32 + lk) ^ ((r & 7) << 3)];
            }
            #pragma unroll
            for (int n = 0; n < 4; ++n) {
                int r = wn + n * 16 + lrow;
                bv[n] = *(const bf16x8*)&bT[(r * 64 + s * 32 + lk) ^ ((r & 7) << 3)];
            }
            #pragma unroll
            for (int m = 0; m < 4; ++m)
                #pragma unroll
                for (int n = 0; n < 4; ++n)
                    acc[m][n] = __builtin_amdgcn_mfma_f32_16x16x32_bf16(af[m], bv[n], acc[m][n], 0, 0, 0);
        }
        __syncthreads();
    }
    // epilogue: inverse output permutation per angle, bias+relu, NHWC scatter
    #pragma unroll
    for (int m = 0; m < 4; ++m)
        #pragma unroll
        for (int j = 0; j < 4; ++j) {
            int row = m0 + wm + m * 16 + ((l >> 4) << 2) + j;
            if (row < 61504) {
                int b = row / 961; int rem = row - b * 961;
                int p = rem / 31;  int q = rem - p * 31;
                #pragma unroll
                for (int n = 0; n < 4; ++n) {
                    int col = wn + n * 16 + lrow;
                    int a = col >> 5, oc = col & 31;
                    int oh, ow;
                    switch (a) {
                        case 0:  oh = p;      ow = q;      break;
                        case 1:  oh = 30 - q; ow = p;      break;
                        case 2:  oh = 30 - p; ow = 30 - q; break;
                        default: oh = q;      ow = 30 - p; break;
                    }
                    float v = acc[m][n][j] + bias[oc];
                    v = v > 0.f ? v : 0.f;
                    act1[(((a << 6) + b) * 961 + oh * 31 + ow) * 32 + oc] = f2bf(v);
                }
            }
        }
}

// ---------------- conv2/conv3: NHWC bf16 in/out, MFMA ----------------------
template<int IC, int IH, int IW, int KH, int KW, int S, int OH, int OW>
__global__ __launch_bounds__(256) void conv_mfma(const ushort* __restrict__ in,
                                                 const ushort* __restrict__ wr,
                                                 const float* __restrict__ bias,
                                                 ushort* __restrict__ out)
{
    constexpr int BK  = KW * IC;
    constexpr int NCH = BK / 8;
    __shared__ ushort aT[128 * BK];
    __shared__ ushort bT[64 * BK];
    const int t  = threadIdx.x;
    const int m0 = blockIdx.x * 128;
    const int wid = t >> 6, l = t & 63;
    const int lrow = l & 15, lk = (l >> 4) << 3;

    f32x4 acc[2][4] = {};
    for (int kh = 0; kh < KH; ++kh) {
        #pragma unroll
        for (int j = 0; j < 128 * NCH / 256; ++j) {
            int tau = j * 256 + t;
            int row = tau / NCH, c = tau - row * NCH;
            int m   = m0 + row;
            int n   = m / (OH * OW); int rem = m - n * (OH * OW);
            int oh  = rem / OW; int ow = rem - oh * OW;
            bf16x8 v = *(const bf16x8*)&in[((n * IH + oh * S + kh) * IW + ow * S) * IC + c * 8];
            *(bf16x8*)&aT[(row * BK + c * 8) ^ ((row & 7) << 3)] = v;
        }
        #pragma unroll
        for (int j = 0; j < 64 * NCH / 256; ++j) {
            int tau = j * 256 + t;
            int row = tau / NCH, c = tau - row * NCH;
            bf16x8 v = *(const bf16x8*)&wr[row * (KH * BK) + kh * BK + c * 8];
            *(bf16x8*)&bT[(row * BK + c * 8) ^ ((row & 7) << 3)] = v;
        }
        __syncthreads();
        #pragma unroll
        for (int s = 0; s < BK / 32; ++s) {
            bf16x8 af[2], bv[4];
            #pragma unroll
            for (int m = 0; m < 2; ++m) {
                int r = wid * 32 + m * 16 + lrow;
                af[m] = *(const bf16x8*)&aT[(r * BK + s * 32 + lk) ^ ((r & 7) << 3)];
            }
            #pragma unroll
            for (int n = 0; n < 4; ++n) {
                int r = n * 16 + lrow;
                bv[n] = *(const bf16x8*)&bT[(r * BK + s * 32 + lk) ^ ((r & 7) << 3)];
            }
            #pragma unroll
            for (int m = 0; m < 2; ++m)
                #pragma unroll
                for (int n = 0; n < 4; ++n)
                    acc[m][n] = __builtin_amdgcn_mfma_f32_16x16x32_bf16(af[m], bv[n], acc[m][n], 0, 0, 0);
        }
        __syncthreads();
    }
    #pragma unroll
    for (int m = 0; m < 2; ++m)
        #pragma unroll
        for (int n = 0; n < 4; ++n)
            #pragma unroll
            for (int j = 0; j < 4; ++j) {
                int row = m0 + wid * 32 + m * 16 + ((l >> 4) << 2) + j;
                int col = n * 16 + lrow;
                float v = acc[m][n][j] + bias[col];
                v = v > 0.f ? v : 0.f;
                out[row * 64 + col] = f2bf(v);
            }
}

// ---------------- fc1: [256,9216]x[512,9216]^T bf16 MFMA, split-K=8 --------
__global__ __launch_bounds__(256) void fc1_mfma(const ushort* __restrict__ A,
                                                const ushort* __restrict__ W,
                                                float* __restrict__ hpart)
{
    __shared__ ushort aT[64 * 64];
    __shared__ ushort bT[64 * 64];
    const int t  = threadIdx.x;
    const int m0 = blockIdx.x * 64, n0 = blockIdx.y * 64;
    const int z  = blockIdx.z;
    const int kb = z * 1152;
    const int wid = t >> 6, l = t & 63;
    const int lrow = l & 15, lk = (l >> 4) << 3;
    const int wm = (wid >> 1) * 32, wn = (wid & 1) * 32;

    f32x4 acc[2][2] = {};
    for (int k0 = 0; k0 < 1152; k0 += 64) {
        #pragma unroll
        for (int j = 0; j < 2; ++j) {
            int tau = j * 256 + t;
            int row = tau >> 3, c = tau & 7;
            bf16x8 v = *(const bf16x8*)&A[(m0 + row) * 9216 + kb + k0 + c * 8];
            *(bf16x8*)&aT[(row * 64 + c * 8) ^ ((row & 7) << 3)] = v;
        }
        #pragma unroll
        for (int j = 0; j < 2; ++j) {
            int tau = j * 256 + t;
            int row = tau >> 3, c = tau & 7;
            bf16x8 v = *(const bf16x8*)&W[(n0 + row) * 9216 + kb + k0 + c * 8];
            *(bf16x8*)&bT[(row * 64 + c * 8) ^ ((row & 7) << 3)] = v;
        }
        __syncthreads();
        #pragma unroll
        for (int s = 0; s < 2; ++s) {
            bf16x8 af[2], bv[2];
            #pragma unroll
            for (int m = 0; m < 2; ++m) {
                int r = wm + m * 16 + lrow;
                af[m] = *(const bf16x8*)&aT[(r * 64 + s * 32 + lk) ^ ((r & 7) << 3)];
            }
            #pragma unroll
            for (int n = 0; n < 2; ++n) {
                int r = wn + n * 16 + lrow;
                bv[n] = *(const bf16x8*)&bT[(r * 64 + s * 32 + lk) ^ ((r & 7) << 3)];
            }
            #pragma unroll
            for (int m = 0; m < 2; ++m)
                #pragma unroll
                for (int n = 0; n < 2; ++n)
                    acc[m][n] = __builtin_amdgcn_mfma_f32_16x16x32_bf16(af[m], bv[n], acc[m][n], 0, 0, 0);
        }
        __syncthreads();
    }
    #pragma unroll
    for (int m = 0; m < 2; ++m)
        #pragma unroll
        for (int n = 0; n < 2; ++n)
            #pragma unroll
            for (int j = 0; j < 4; ++j) {
                int row = m0 + wm + m * 16 + ((l >> 4) << 2) + j;
                int col = n0 + wn + n * 16 + lrow;
                hpart[(z * 256 + row) * 512 + col] = acc[m][n][j];
            }
}

// ---------------- fc2: combine split-K, bias, relu, final 512-dot ----------
__global__ __launch_bounds__(256) void fc2_kernel(const float* __restrict__ hp,
                                                  const float* __restrict__ b1,
                                                  const float* __restrict__ W2,
                                                  const float* __restrict__ b2,
                                                  float* __restrict__ logits)
{
    __shared__ float s[512];
    const int i = blockIdx.x;
    const int t = threadIdx.x;
    for (int k = t; k < 512; k += 256) {
        float v = b1[k];
        #pragma unroll
        for (int z = 0; z < 8; ++z) v += hp[(z * 256 + i) * 512 + k];
        s[k] = v > 0.f ? v : 0.f;
    }
    __syncthreads();
    const int j = t >> 6;
    const int l = t & 63;
    float p = 0.f;
    #pragma unroll
    for (int q = 0; q < 8; ++q) p += s[l + q * 64] * W2[j * 512 + l + q * 64];
    #pragma unroll
    for (int off = 32; off > 0; off >>= 1) p += __shfl_xor(p, off);
    if (l == 0) logits[i * 4 + j] = p + b2[j];
}

// ---------------------------------------------------------------------------
extern "C" void kernel_launch(void* const* d_in, const int* in_sizes, int n_in,
                              void* d_out, int out_size, void* d_ws, size_t ws_size,
                              hipStream_t stream)
{
    const float* obs   = (const float*)d_in[0];
    const float* w1    = (const float*)d_in[1];
    const float* b1    = (const float*)d_in[2];
    const float* w2    = (const float*)d_in[3];
    const float* b2    = (const float*)d_in[4];
    const float* w3    = (const float*)d_in[5];
    const float* b3    = (const float*)d_in[6];
    const float* fc1_w = (const float*)d_in[7];
    const float* fc1_b = (const float*)d_in[8];
    const float* fc2_w = (const float*)d_in[9];
    const float* fc2_b = (const float*)d_in[10];

    float* out    = (float*)d_out;
    float* logits = out;
    float* labels = out + 1024;
    float* rot    = out + 1280;

    char* ws = (char*)d_ws;
    ushort* act1  = (ushort*)(ws);                       // 15,745,024 B
    ushort* act2  = (ushort*)(ws + 15745024);            //  6,422,528 B
    ushort* act3  = (ushort*)(ws + 22167552);            //  4,718,592 B
    ushort* w2r   = (ushort*)(ws + 26886144);            //     65,536 B
    ushort* w3r   = (ushort*)(ws + 26951680);            //     73,728 B
    ushort* fc1wr = (ushort*)(ws + 27025408);            //  9,437,184 B
    float*  hpart = (float*) (ws + 36462592);            //  4,194,304 B
    ushort* w1r   = (ushort*)(ws + 36462592);            // 49,152 B, dead before fc1 writes hpart

    prep_misc<<<369, 256, 0, stream>>>(w1, w2, w3, w1r, w2r, w3r, labels);
    prep_fc1w<<<512, 256, 0, stream>>>(fc1_w, fc1wr);

    rotate_tiled<<<12288, 256, 0, stream>>>(obs, rot);

    conv1_mfma<<<481, 256, 0, stream>>>(obs, w1r, b1, act1);
    conv_mfma<32, 31, 31, 4, 4, 2, 14, 14><<<392, 256, 0, stream>>>(act1, w2r, b2, act2);
    conv_mfma<64, 14, 14, 3, 3, 1, 12, 12><<<288, 256, 0, stream>>>(act2, w3r, b3, act3);

    fc1_mfma<<<dim3(4, 8, 8), 256, 0, stream>>>(act3, fc1wr, hpart);
    fc2_kernel<<<256, 256, 0, stream>>>(hpart, fc1_b, fc2_w, fc2_b, logits);
}

// Round 4
// 91.142 us; speedup vs baseline: 5.0182x; 1.1507x over previous
//
#include <hip/hip_runtime.h>

// ---------------------------------------------------------------------------
// AuxModelImageRotation round 4.
// - stage1 fuses: prep_fc1w + weight preps/labels + rotate (1-read-4-write).
// - conv1/conv2/conv3: gather addressing hoisted out of K loops.
// - 6 kernel launches total (was 8).
// Output: [logits 1024][labels 256][rotated 256*3*128*128] f32.
// ---------------------------------------------------------------------------

typedef short bf16x8 __attribute__((ext_vector_type(8)));
typedef float f32x4  __attribute__((ext_vector_type(4)));

__device__ __forceinline__ ushort f2bf(float f) {
    uint u = __float_as_uint(f);
    u += 0x7fffu + ((u >> 16) & 1u);
    return (ushort)(u >> 16);
}

// ---------------- stage1: prep_fc1w | preps+labels | rotate ----------------
// blocks [0,512): fc1_w transpose->bf16 ; [512,881): w1r/w2r/w3r/labels ;
// [881,3953): rotation, one source tile -> 4 rotated dest tiles.
__global__ __launch_bounds__(256) void stage1(const float* __restrict__ obs,
                                              const float* __restrict__ w1,
                                              const float* __restrict__ w2,
                                              const float* __restrict__ w3,
                                              const float* __restrict__ fc1_w,
                                              float* __restrict__ rot,
                                              ushort* __restrict__ w1r,
                                              ushort* __restrict__ w2r,
                                              ushort* __restrict__ w3r,
                                              ushort* __restrict__ fc1wr,
                                              float* __restrict__ lab)
{
    __shared__ __align__(16) char smem[36864];
    const int bx = blockIdx.x, t = threadIdx.x;

    if (bx < 512) {
        // fc1_w [512][64*144] (c,p) -> bf16 [512][144*64] (p,c)
        float* s = (float*)smem;
        const int n = bx;
        #pragma unroll
        for (int j = 0; j < 9; ++j) {
            int i = (j * 256 + t) * 4;
            *(float4*)&s[i] = *(const float4*)&fc1_w[n * 9216 + i];
        }
        __syncthreads();
        uint* op = (uint*)(fc1wr + n * 9216);
        #pragma unroll
        for (int j = 0; j < 18; ++j) {
            int q  = j * 256 + t;
            int jj = q * 2;
            int ic = jj & 63, p = jj >> 6;
            uint lo = f2bf(s[ic * 144 + p]);
            uint hi = f2bf(s[(ic + 1) * 144 + p]);
            op[q] = lo | (hi << 16);
        }
    } else if (bx < 881) {
        const int bxx = bx - 512;
        if (bxx < 128) {                      // w2 -> (oc, kh, kw, ic) bf16
            int i = bxx * 256 + t;
            int ic = i & 31, kw = (i >> 5) & 3, kh = (i >> 7) & 3, oc = i >> 9;
            w2r[i] = f2bf(w2[((oc * 32 + ic) * 4 + kh) * 4 + kw]);
        } else if (bxx < 272) {               // w3 -> (oc, kh, kw, ic) bf16
            int i = (bxx - 128) * 256 + t;
            int ic = i & 63, r = i >> 6;
            int kw = r % 3, r2 = r / 3;
            int kh = r2 % 3, oc = r2 / 3;
            w3r[i] = f2bf(w3[((oc * 64 + ic) * 3 + kh) * 3 + kw]);
        } else if (bxx < 368) {               // w1 rotated: [a*32+oc][ic*64+a8*8+b8]
            int i = (bxx - 272) * 256 + t;
            int n = i / 192, r = i - n * 192;
            int ic = r >> 6, a8 = (r >> 3) & 7, b8 = r & 7;
            int a = n >> 5, oc = n & 31;
            int kh, kw;
            switch (a) {
                case 0:  kh = a8;     kw = b8;     break;
                case 1:  kh = 7 - b8; kw = a8;     break;
                case 2:  kh = 7 - a8; kw = 7 - b8; break;
                default: kh = b8;     kw = 7 - a8; break;
            }
            w1r[i] = f2bf(w1[((oc * 3 + ic) * 8 + kh) * 8 + kw]);
        } else {
            lab[t] = (float)(t >> 6);
        }
    } else {
        // rotation: source tile (b,c,th,tw); write 4 rotated dest tiles.
        float (*sN)[36] = (float(*)[36])smem;           // 4608 B
        float (*sT)[33] = (float(*)[33])(smem + 4608);  // 4224 B, sT[ws][hs]
        const int bb   = bx - 881;                      // 0..3071
        const int tile = bb & 15;
        const int cimg = bb >> 4;                       // 0..191
        const int c = cimg % 3, b = cimg / 3;
        const int h0s = (tile >> 2) * 32, w0s = (tile & 3) * 32;
        const int rs = t >> 3, w4 = (t & 7) * 4;

        const float* src = obs + ((b * 3 + c) << 14);
        float4 v = *(const float4*)&src[((h0s + rs) << 7) + w0s + w4];
        *(float4*)&sN[rs][w4] = v;
        sT[w4 + 0][rs] = v.x; sT[w4 + 1][rs] = v.y;
        sT[w4 + 2][rs] = v.z; sT[w4 + 3][rs] = v.w;

        float* d0 = rot + (((      b) * 3 + c) << 14);
        float* d1 = rot + ((( 64 + b) * 3 + c) << 14);
        float* d2 = rot + (((128 + b) * 3 + c) << 14);
        float* d3 = rot + (((192 + b) * 3 + c) << 14);

        // a=0: straight copy (register)
        *(float4*)&d0[((h0s + rs) << 7) + w0s + w4] = v;
        __syncthreads();
        // a=1: out[h,w]=in[w,127-h]; dest tile (96-w0s, h0s); val=sT[31-rs][w4+i]
        float4 o;
        o.x = sT[31 - rs][w4 + 0]; o.y = sT[31 - rs][w4 + 1];
        o.z = sT[31 - rs][w4 + 2]; o.w = sT[31 - rs][w4 + 3];
        *(float4*)&d1[((96 - w0s + rs) << 7) + h0s + w4] = o;
        // a=2: out[h,w]=in[127-h,127-w]; dest (96-h0s, 96-w0s); val=sN[31-rs][31-w4-i]
        o.x = sN[31 - rs][31 - w4 - 0]; o.y = sN[31 - rs][31 - w4 - 1];
        o.z = sN[31 - rs][31 - w4 - 2]; o.w = sN[31 - rs][31 - w4 - 3];
        *(float4*)&d2[((96 - h0s + rs) << 7) + (96 - w0s) + w4] = o;
        // a=3: out[h,w]=in[127-w,h]; dest (w0s, 96-h0s); val=sT[rs][31-w4-i]
        o.x = sT[rs][31 - w4 - 0]; o.y = sT[rs][31 - w4 - 1];
        o.z = sT[rs][31 - w4 - 2]; o.w = sT[rs][31 - w4 - 3];
        *(float4*)&d3[((w0s + rs) << 7) + (96 - h0s) + w4] = o;
    }
}

// ---------------- conv1: obs f32 -> act1 NHWC bf16 via rotated weights -----
// M=61504 (b,p,q over 64 imgs), N=128 (a*32+oc), K=192 (ic,dh,dw). BM=BN=128.
__global__ __launch_bounds__(256) void conv1_mfma(const float* __restrict__ obs,
                                                  const ushort* __restrict__ w1r,
                                                  const float* __restrict__ bias,
                                                  ushort* __restrict__ act1)
{
    __shared__ ushort aT[128 * 64];
    __shared__ ushort bT[128 * 64];
    const int t   = threadIdx.x;
    const int m0  = blockIdx.x * 128;
    const int wid = t >> 6, l = t & 63;
    const int lrow = l & 15, lk = (l >> 4) << 3;
    const int wm = (wid >> 1) * 64, wn = (wid & 1) * 64;

    // hoisted gather bases
    int abase[4], aoff[4], bbase[4], boff[4];
    #pragma unroll
    for (int j = 0; j < 4; ++j) {
        int cid = j * 256 + t;
        int row = cid >> 3, c = cid & 7;
        int m = m0 + row; m = m < 61504 ? m : 61503;
        int b = m / 961; int rem = m - b * 961;
        int p = rem / 31; int q = rem - p * 31;
        abase[j] = ((b * 3) << 14) + ((p * 4 + c) << 7) + q * 4;
        aoff[j]  = (row * 64 + c * 8) ^ ((row & 7) << 3);
        bbase[j] = row * 192 + c * 8;
        boff[j]  = aoff[j];
    }

    f32x4 acc[4][4] = {};
    for (int ic = 0; ic < 3; ++ic) {
        #pragma unroll
        for (int j = 0; j < 4; ++j) {
            const float* src = obs + abase[j] + (ic << 14);
            float4 v0 = *(const float4*)src;
            float4 v1 = *(const float4*)(src + 4);
            bf16x8 pk;
            pk[0] = (short)f2bf(v0.x); pk[1] = (short)f2bf(v0.y);
            pk[2] = (short)f2bf(v0.z); pk[3] = (short)f2bf(v0.w);
            pk[4] = (short)f2bf(v1.x); pk[5] = (short)f2bf(v1.y);
            pk[6] = (short)f2bf(v1.z); pk[7] = (short)f2bf(v1.w);
            *(bf16x8*)&aT[aoff[j]] = pk;
        }
        #pragma unroll
        for (int j = 0; j < 4; ++j)
            *(bf16x8*)&bT[boff[j]] = *(const bf16x8*)&w1r[bbase[j] + ic * 64];
        __syncthreads();
        #pragma unroll
        for (int s = 0; s < 2; ++s) {
            bf16x8 af[4], bv[4];
            #pragma unroll
            for (int m = 0; m < 4; ++m) {
                int r = wm + m * 16 + lrow;
                af[m] = *(const bf16x8*)&aT[(r * 64 + s * 32 + lk) ^ ((r & 7) << 3)];
            }
            #pragma unroll
            for (int n = 0; n < 4; ++n) {
                int r = wn + n * 16 + lrow;
                bv[n] = *(const bf16x8*)&bT[(r * 64 + s * 32 + lk) ^ ((r & 7) << 3)];
            }
            #pragma unroll
            for (int m = 0; m < 4; ++m)
                #pragma unroll
                for (int n = 0; n < 4; ++n)
                    acc[m][n] = __builtin_amdgcn_mfma_f32_16x16x32_bf16(af[m], bv[n], acc[m][n], 0, 0, 0);
        }
        __syncthreads();
    }
    // epilogue: inverse output permutation per angle, bias+relu, NHWC scatter
    #pragma unroll
    for (int m = 0; m < 4; ++m)
        #pragma unroll
        for (int j = 0; j < 4; ++j) {
            int row = m0 + wm + m * 16 + ((l >> 4) << 2) + j;
            if (row < 61504) {
                int b = row / 961; int rem = row - b * 961;
                int p = rem / 31;  int q = rem - p * 31;
                #pragma unroll
                for (int n = 0; n < 4; ++n) {
                    int col = wn + n * 16 + lrow;
                    int a = col >> 5, oc = col & 31;
                    int oh, ow;
                    switch (a) {
                        case 0:  oh = p;      ow = q;      break;
                        case 1:  oh = 30 - q; ow = p;      break;
                        case 2:  oh = 30 - p; ow = 30 - q; break;
                        default: oh = q;      ow = 30 - p; break;
                    }
                    float v = acc[m][n][j] + bias[oc];
                    v = v > 0.f ? v : 0.f;
                    act1[(((a << 6) + b) * 961 + oh * 31 + ow) * 32 + oc] = f2bf(v);
                }
            }
        }
}

// ---------------- conv2/conv3: NHWC bf16 in/out, MFMA, hoisted gathers -----
template<int IC, int IH, int IW, int KH, int KW, int S, int OH, int OW>
__global__ __launch_bounds__(256) void conv_mfma(const ushort* __restrict__ in,
                                                 const ushort* __restrict__ wr,
                                                 const float* __restrict__ bias,
                                                 ushort* __restrict__ out)
{
    constexpr int BK  = KW * IC;
    constexpr int NCH = BK / 8;
    constexpr int AJ  = 128 * NCH / 256;
    constexpr int BJ  = 64 * NCH / 256;
    __shared__ ushort aT[128 * BK];
    __shared__ ushort bT[64 * BK];
    const int t  = threadIdx.x;
    const int m0 = blockIdx.x * 128;
    const int wid = t >> 6, l = t & 63;
    const int lrow = l & 15, lk = (l >> 4) << 3;

    int abase[AJ], aoff[AJ], bbase[BJ], boff[BJ];
    #pragma unroll
    for (int j = 0; j < AJ; ++j) {
        int tau = j * 256 + t;
        int row = tau / NCH, c = tau - row * NCH;
        int m   = m0 + row;
        int n   = m / (OH * OW); int rem = m - n * (OH * OW);
        int oh  = rem / OW; int ow = rem - oh * OW;
        abase[j] = ((n * IH + oh * S) * IW + ow * S) * IC + c * 8;
        aoff[j]  = (row * BK + c * 8) ^ ((row & 7) << 3);
    }
    #pragma unroll
    for (int j = 0; j < BJ; ++j) {
        int tau = j * 256 + t;
        int row = tau / NCH, c = tau - row * NCH;
        bbase[j] = row * (KH * BK) + c * 8;
        boff[j]  = (row * BK + c * 8) ^ ((row & 7) << 3);
    }

    f32x4 acc[2][4] = {};
    for (int kh = 0; kh < KH; ++kh) {
        #pragma unroll
        for (int j = 0; j < AJ; ++j)
            *(bf16x8*)&aT[aoff[j]] = *(const bf16x8*)&in[abase[j] + kh * (IW * IC)];
        #pragma unroll
        for (int j = 0; j < BJ; ++j)
            *(bf16x8*)&bT[boff[j]] = *(const bf16x8*)&wr[bbase[j] + kh * BK];
        __syncthreads();
        #pragma unroll
        for (int s = 0; s < BK / 32; ++s) {
            bf16x8 af[2], bv[4];
            #pragma unroll
            for (int m = 0; m < 2; ++m) {
                int r = wid * 32 + m * 16 + lrow;
                af[m] = *(const bf16x8*)&aT[(r * BK + s * 32 + lk) ^ ((r & 7) << 3)];
            }
            #pragma unroll
            for (int n = 0; n < 4; ++n) {
                int r = n * 16 + lrow;
                bv[n] = *(const bf16x8*)&bT[(r * BK + s * 32 + lk) ^ ((r & 7) << 3)];
            }
            #pragma unroll
            for (int m = 0; m < 2; ++m)
                #pragma unroll
                for (int n = 0; n < 4; ++n)
                    acc[m][n] = __builtin_amdgcn_mfma_f32_16x16x32_bf16(af[m], bv[n], acc[m][n], 0, 0, 0);
        }
        __syncthreads();
    }
    #pragma unroll
    for (int m = 0; m < 2; ++m)
        #pragma unroll
        for (int n = 0; n < 4; ++n)
            #pragma unroll
            for (int j = 0; j < 4; ++j) {
                int row = m0 + wid * 32 + m * 16 + ((l >> 4) << 2) + j;
                int col = n * 16 + lrow;
                float v = acc[m][n][j] + bias[col];
                v = v > 0.f ? v : 0.f;
                out[row * 64 + col] = f2bf(v);
            }
}

// ---------------- fc1: [256,9216]x[512,9216]^T bf16 MFMA, split-K=8 --------
__global__ __launch_bounds__(256) void fc1_mfma(const ushort* __restrict__ A,
                                                const ushort* __restrict__ W,
                                                float* __restrict__ hpart)
{
    __shared__ ushort aT[64 * 64];
    __shared__ ushort bT[64 * 64];
    const int t  = threadIdx.x;
    const int m0 = blockIdx.x * 64, n0 = blockIdx.y * 64;
    const int z  = blockIdx.z;
    const int kb = z * 1152;
    const int wid = t >> 6, l = t & 63;
    const int lrow = l & 15, lk = (l >> 4) << 3;
    const int wm = (wid >> 1) * 32, wn = (wid & 1) * 32;

    f32x4 acc[2][2] = {};
    for (int k0 = 0; k0 < 1152; k0 += 64) {
        #pragma unroll
        for (int j = 0; j < 2; ++j) {
            int tau = j * 256 + t;
            int row = tau >> 3, c = tau & 7;
            bf16x8 v = *(const bf16x8*)&A[(m0 + row) * 9216 + kb + k0 + c * 8];
            *(bf16x8*)&aT[(row * 64 + c * 8) ^ ((row & 7) << 3)] = v;
        }
        #pragma unroll
        for (int j = 0; j < 2; ++j) {
            int tau = j * 256 + t;
            int row = tau >> 3, c = tau & 7;
            bf16x8 v = *(const bf16x8*)&W[(n0 + row) * 9216 + kb + k0 + c * 8];
            *(bf16x8*)&bT[(row * 64 + c * 8) ^ ((row & 7) << 3)] = v;
        }
        __syncthreads();
        #pragma unroll
        for (int s = 0; s < 2; ++s) {
            bf16x8 af[2], bv[2];
            #pragma unroll
            for (int m = 0; m < 2; ++m) {
                int r = wm + m * 16 + lrow;
                af[m] = *(const bf16x8*)&aT[(r * 64 + s * 32 + lk) ^ ((r & 7) << 3)];
            }
            #pragma unroll
            for (int n = 0; n < 2; ++n) {
                int r = wn + n * 16 + lrow;
                bv[n] = *(const bf16x8*)&bT[(r * 64 + s * 32 + lk) ^ ((r & 7) << 3)];
            }
            #pragma unroll
            for (int m = 0; m < 2; ++m)
                #pragma unroll
                for (int n = 0; n < 2; ++n)
                    acc[m][n] = __builtin_amdgcn_mfma_f32_16x16x32_bf16(af[m], bv[n], acc[m][n], 0, 0, 0);
        }
        __syncthreads();
    }
    #pragma unroll
    for (int m = 0; m < 2; ++m)
        #pragma unroll
        for (int n = 0; n < 2; ++n)
            #pragma unroll
            for (int j = 0; j < 4; ++j) {
                int row = m0 + wm + m * 16 + ((l >> 4) << 2) + j;
                int col = n0 + wn + n * 16 + lrow;
                hpart[(z * 256 + row) * 512 + col] = acc[m][n][j];
            }
}

// ---------------- fc2: combine split-K, bias, relu, final 512-dot ----------
__global__ __launch_bounds__(256) void fc2_kernel(const float* __restrict__ hp,
                                                  const float* __restrict__ b1,
                                                  const float* __restrict__ W2,
                                                  const float* __restrict__ b2,
                                                  float* __restrict__ logits)
{
    __shared__ float s[512];
    const int i = blockIdx.x;
    const int t = threadIdx.x;
    for (int k = t; k < 512; k += 256) {
        float v = b1[k];
        #pragma unroll
        for (int z = 0; z < 8; ++z) v += hp[(z * 256 + i) * 512 + k];
        s[k] = v > 0.f ? v : 0.f;
    }
    __syncthreads();
    const int j = t >> 6;
    const int l = t & 63;
    float p = 0.f;
    #pragma unroll
    for (int q = 0; q < 8; ++q) p += s[l + q * 64] * W2[j * 512 + l + q * 64];
    #pragma unroll
    for (int off = 32; off > 0; off >>= 1) p += __shfl_xor(p, off);
    if (l == 0) logits[i * 4 + j] = p + b2[j];
}

// ---------------------------------------------------------------------------
extern "C" void kernel_launch(void* const* d_in, const int* in_sizes, int n_in,
                              void* d_out, int out_size, void* d_ws, size_t ws_size,
                              hipStream_t stream)
{
    const float* obs   = (const float*)d_in[0];
    const float* w1    = (const float*)d_in[1];
    const float* b1    = (const float*)d_in[2];
    const float* w2    = (const float*)d_in[3];
    const float* b2    = (const float*)d_in[4];
    const float* w3    = (const float*)d_in[5];
    const float* b3    = (const float*)d_in[6];
    const float* fc1_w = (const float*)d_in[7];
    const float* fc1_b = (const float*)d_in[8];
    const float* fc2_w = (const float*)d_in[9];
    const float* fc2_b = (const float*)d_in[10];

    float* out    = (float*)d_out;
    float* logits = out;
    float* labels = out + 1024;
    float* rot    = out + 1280;

    char* ws = (char*)d_ws;
    ushort* act1  = (ushort*)(ws);                       // 15,745,024 B
    ushort* act2  = (ushort*)(ws + 15745024);            //  6,422,528 B
    ushort* act3  = (ushort*)(ws + 22167552);            //  4,718,592 B
    ushort* w2r   = (ushort*)(ws + 26886144);            //     65,536 B
    ushort* w3r   = (ushort*)(ws + 26951680);            //     73,728 B
    ushort* fc1wr = (ushort*)(ws + 27025408);            //  9,437,184 B
    float*  hpart = (float*) (ws + 36462592);            //  4,194,304 B
    ushort* w1r   = (ushort*)(ws + 36462592);            // 49,152 B, dead before fc1 writes hpart

    stage1<<<3953, 256, 0, stream>>>(obs, w1, w2, w3, fc1_w,
                                     rot, w1r, w2r, w3r, fc1wr, labels);

    conv1_mfma<<<481, 256, 0, stream>>>(obs, w1r, b1, act1);
    conv_mfma<32, 31, 31, 4, 4, 2, 14, 14><<<392, 256, 0, stream>>>(act1, w2r, b2, act2);
    conv_mfma<64, 14, 14, 3, 3, 1, 12, 12><<<288, 256, 0, stream>>>(act2, w3r, b3, act3);

    fc1_mfma<<<dim3(4, 8, 8), 256, 0, stream>>>(act3, fc1wr, hpart);
    fc2_kernel<<<256, 256, 0, stream>>>(hpart, fc1_b, fc2_w, fc2_b, logits);
}